// Round 5
// baseline (547.099 us; speedup 1.0000x reference)
//
#include <hip/hip_runtime.h>

typedef unsigned int u32;
typedef unsigned short u16;
typedef __attribute__((ext_vector_type(8))) short bf16x8;  // 8 bf16 = 4 VGPRs
typedef __attribute__((ext_vector_type(4))) float f32x4;

#define KN 8192
#define DD 256
#define HW 1024
#define NP 32768
#define SPLITS 2
#define KSPLIT 4096
#define PXT 128
#define NTT 128

__device__ __forceinline__ u16 rne_bf16(float x) {
    u32 u = __float_as_uint(x);
    return (u16)((u + 0x7FFF + ((u >> 16) & 1)) >> 16);
}

__device__ __forceinline__ void glds16(const void* g, void* ldsbase) {
    __builtin_amdgcn_global_load_lds((const __attribute__((address_space(1))) u32*)g,
                                     (__attribute__((address_space(3))) u32*)ldsbase, 16, 0, 0);
}

// ---------------- e2f[k] = sum_d e[d,k]^2 (exact fp32) ----------------
__global__ void enorm_kernel(const float* __restrict__ e, float* __restrict__ e2f) {
    int k = blockIdx.x * blockDim.x + threadIdx.x;
    float acc = 0.f;
#pragma unroll 8
    for (int d = 0; d < DD; ++d) {
        float v = e[(size_t)d * KN + k];
        acc = fmaf(v, v, acc);
    }
    e2f[k] = acc;
}

// ------- eT[k][d] = bf16(e[d][k]);  eTf[k][d] = fp32 e[d][k] (for rescoring) -------
__global__ void prep_eT_kernel(const float* __restrict__ e, u16* __restrict__ eT,
                               float* __restrict__ eTf) {
    __shared__ float tt[64][65];
    const int t = threadIdx.x;
    const int kt = blockIdx.x;   // 0..127
    const int dt = blockIdx.y;   // 0..3
    const float* ep = e + (size_t)(dt * 64) * KN + kt * 64;
    {
        int k = t & 63, d0 = t >> 6;
#pragma unroll
        for (int j = 0; j < 16; ++j) tt[d0 + j * 4][k] = ep[(size_t)(d0 + j * 4) * KN + k];
    }
    __syncthreads();
    int k = t >> 2, c0 = (t & 3) * 16;
    u16 hi[16];
    float fv[16];
#pragma unroll
    for (int j = 0; j < 16; ++j) {
        float v = tt[c0 + j][k];
        fv[j] = v;
        hi[j] = rne_bf16(v);
    }
    u16* rowp = eT + (size_t)(kt * 64 + k) * 256 + dt * 64 + c0;
    *(uint4*)(rowp) = *(uint4*)(hi);
    *(uint4*)(rowp + 8) = *(uint4*)(hi + 8);
    float* rowpf = eTf + (size_t)(kt * 64 + k) * 256 + dt * 64 + c0;
#pragma unroll
    for (int j = 0; j < 4; ++j) *(float4*)(rowpf + j * 4) = *(float4*)(fv + j * 4);
}

// ---------------- A[n][d] = bf16(z[b,d,h,w]), n = b*1024 + h*32 + w ----------------
__global__ void prep_A_kernel(const float* __restrict__ z, u16* __restrict__ A) {
    __shared__ float tt[64][65];
    const int t = threadIdx.x;
    const int pt = blockIdx.x;   // 0..15
    const int dt = blockIdx.y;   // 0..3
    const int b  = blockIdx.z;   // 0..31
    const float* zp = z + (size_t)b * (DD * HW) + (size_t)(dt * 64) * HW + pt * 64;
    {
        int p = t & 63, d0 = t >> 6;
#pragma unroll
        for (int j = 0; j < 16; ++j) tt[d0 + j * 4][p] = zp[(size_t)(d0 + j * 4) * HW + p];
    }
    __syncthreads();
    int p = t >> 2, c0 = (t & 3) * 16;
    int n = b * HW + pt * 64 + p;
    u16 hi[16];
#pragma unroll
    for (int j = 0; j < 16; ++j) hi[j] = rne_bf16(tt[c0 + j][p]);
    u16* rowp = A + (size_t)n * 256 + dt * 64 + c0;
    *(uint4*)(rowp) = *(uint4*)(hi);
    *(uint4*)(rowp + 8) = *(uint4*)(hi + 8);
}

// ---------------- main: MFMA distance GEMM + streaming top-3 argmin ----------------
// XCD-aware mapping: slot = blockIdx&7 -> XCDs 0..3 own split 0, XCDs 4..7 split 1.
// Each XCD keeps its 2 MB eT slice hot in its private L2 and streams A once.
__launch_bounds__(256, 3)
__global__ void argmin_mfma_kernel(const u16* __restrict__ A,   // [32768][256]
                                   const u16* __restrict__ eT,  // [8192][256]
                                   const float* __restrict__ e2f,
                                   int* __restrict__ keys) {    // [3][2][NP]
    __shared__ u16 Ast[PXT * 64];   // 16 KB, XOR-swizzled column slots
    __shared__ u16 Bst[NTT * 64];   // 16 KB
    __shared__ float e2s[KSPLIT];   // 16 KB: this split's e2f slice

    const int t = threadIdx.x;
    const int w = t >> 6;
    const int l = t & 63;
    const int slot  = blockIdx.x & 7;
    const int split = slot >> 2;                       // 0..1
    const int pxt   = (blockIdx.x >> 3) * 4 + (slot & 3);  // 0..255
    const int px0 = pxt * PXT;
    const int kb0 = split * KSPLIT;

    const int swz  = (l & 7) ^ ((l >> 3) & 7);  // staging: fetch global slot swz
    const int srow = l >> 3;                    // row within 8-row group
    const int fr = l & 15;                      // frag row (m or n)
    const int g  = l >> 4;                      // quad -> k slice g*8..g*8+7

    // preload e2f slice (coalesced, before first barrier)
#pragma unroll
    for (int i = 0; i < KSPLIT / 256 / 4; ++i) {
        int q = (t + i * 256) * 4;
        *(float4*)(e2s + q) = *(const float4*)(e2f + kb0 + q);
    }

    int b1[8], b2[8], b3[8];
#pragma unroll
    for (int i = 0; i < 8; ++i) { b1[i] = 0x7FFFFFFF; b2[i] = 0x7FFFFFFF; b3[i] = 0x7FFFFFFF; }

    for (int nt = 0; nt < KSPLIT / NTT; ++nt) {
        const int n0 = kb0 + nt * NTT;
        f32x4 acc[2][8];
#pragma unroll
        for (int mi = 0; mi < 2; ++mi)
#pragma unroll
            for (int ni = 0; ni < 8; ++ni) acc[mi][ni] = (f32x4){0.f, 0.f, 0.f, 0.f};

        for (int kit = 0; kit < 4; ++kit) {
            __syncthreads();
#pragma unroll
            for (int i = 0; i < 4; ++i) {   // A: 128 rows x 64 bf16
                int r0 = w * 32 + i * 8;
                const u16* gp = A + (size_t)(px0 + r0 + srow) * 256 + kit * 64 + swz * 8;
                glds16(gp, &Ast[r0 * 64]);
            }
#pragma unroll
            for (int i = 0; i < 4; ++i) {   // B: 128 codewords x 64 bf16
                int r0 = w * 32 + i * 8;
                const u16* gp = eT + (size_t)(n0 + r0 + srow) * 256 + kit * 64 + swz * 8;
                glds16(gp, &Bst[r0 * 64]);
            }
            __syncthreads();
#pragma unroll
            for (int kc = 0; kc < 2; ++kc) {
                bf16x8 af[2], bfr[8];
#pragma unroll
                for (int mi = 0; mi < 2; ++mi) {
                    int row = w * 32 + mi * 16 + fr;
                    int slt = (kc * 4 + g) ^ (row & 7);
                    af[mi] = *(const bf16x8*)&Ast[row * 64 + slt * 8];
                }
#pragma unroll
                for (int ni = 0; ni < 8; ++ni) {
                    int row = ni * 16 + fr;
                    int slt = (kc * 4 + g) ^ (row & 7);
                    bfr[ni] = *(const bf16x8*)&Bst[row * 64 + slt * 8];
                }
#pragma unroll
                for (int mi = 0; mi < 2; ++mi)
#pragma unroll
                    for (int ni = 0; ni < 8; ++ni)
                        acc[mi][ni] = __builtin_amdgcn_mfma_f32_16x16x32_bf16(
                            af[mi], bfr[ni], acc[mi][ni], 0, 0, 0);
            }
        }

        // epilogue: key = trunc(256*(e2-2s))*8192 + k ; streaming top-3
#pragma unroll
        for (int ni = 0; ni < 8; ++ni) {
            int kcol = n0 + ni * 16 + fr;
            float e2c = e2s[kcol - kb0] * 256.f;
#pragma unroll
            for (int mi = 0; mi < 2; ++mi) {
#pragma unroll
                for (int r = 0; r < 4; ++r) {
                    float d = fmaf(acc[mi][ni][r], -512.f, e2c);
                    int key = (int)d * 8192 + kcol;
                    int i8 = mi * 4 + r;
                    int v1 = min(b1[i8], key);
                    int x  = max(b1[i8], key);
                    int v2 = min(b2[i8], x);
                    int y  = max(b2[i8], x);
                    int v3 = min(b3[i8], y);
                    b1[i8] = v1; b2[i8] = v2; b3[i8] = v3;
                }
            }
        }
    }

    // merge top-3 across the 16 fr-lanes (columns); g-groups hold distinct rows
#pragma unroll
    for (int m = 1; m < 16; m <<= 1) {
#pragma unroll
        for (int i = 0; i < 8; ++i) {
            int a1 = __shfl_xor(b1[i], m, 64);
            int a2 = __shfl_xor(b2[i], m, 64);
            int a3 = __shfl_xor(b3[i], m, 64);
            int m1 = min(b1[i], a1);
            int xx = max(b1[i], a1);
            int mn2 = min(b2[i], a2);
            int m2 = min(xx, mn2);
            int m3 = min(min(max(b2[i], a2), max(xx, mn2)), min(b3[i], a3));
            b1[i] = m1; b2[i] = m2; b3[i] = m3;
        }
    }
    if (fr == 0) {
        int* k1 = keys + split * NP;
        int* k2 = keys + (2 + split) * NP;
        int* k3 = keys + (4 + split) * NP;
#pragma unroll
        for (int mi = 0; mi < 2; ++mi)
#pragma unroll
            for (int r = 0; r < 4; ++r) {
                int row = px0 + w * 32 + mi * 16 + g * 4 + r;
                k1[row] = b1[mi * 4 + r];
                k2[row] = b2[mi * 4 + r];
                k3[row] = b3[mi * 4 + r];
            }
    }
}

// -------- combine: ALWAYS exact-rescore all 6 candidates in fp32 --------
__global__ void combine_kernel(const int* __restrict__ keys,
                               const float* __restrict__ z,
                               const float* __restrict__ eTf,
                               const float* __restrict__ e2f,
                               int* __restrict__ idx) {
    __shared__ float zt[DD * 65];     // padded: zt[d*65+p]
    const int t = threadIdx.x;
    const int n0 = blockIdx.x * 64;   // 64 pixels per block
    const float* zp = z + (size_t)(n0 >> 10) * (DD * HW) + (n0 & (HW - 1));
    for (int i = t; i < DD * 64; i += 256) {
        int d = i >> 6, p = i & 63;
        zt[d * 65 + p] = zp[(size_t)d * HW + p];   // coalesced
    }
    __syncthreads();

    const int l = t & 63, w = t >> 6;
    for (int q = 0; q < 16; ++q) {
        const int p = w * 16 + q;
        const int px = n0 + p;
        float zr0 = zt[(l      ) * 65 + p];
        float zr1 = zt[(l +  64) * 65 + p];
        float zr2 = zt[(l + 128) * 65 + p];
        float zr3 = zt[(l + 192) * 65 + p];
        float bv = 3.4e38f;
        int   bk = 0x7FFFFFFF;
#pragma unroll
        for (int c = 0; c < 6; ++c) {
            int k = keys[c * NP + px] & 8191;      // px wave-uniform -> scalar load
            const float* er = eTf + (size_t)k * 256;
            float acc = zr0 * er[l];
            acc = fmaf(zr1, er[l + 64], acc);
            acc = fmaf(zr2, er[l + 128], acc);
            acc = fmaf(zr3, er[l + 192], acc);
#pragma unroll
            for (int m = 1; m < 64; m <<= 1) acc += __shfl_xor(acc, m, 64);
            float d = fmaf(-2.f, acc, e2f[k]);     // exact fp32 (minus const ||z||^2)
            if (d < bv || (d == bv && k < bk)) { bv = d; bk = k; }
        }
        if (l == 0) idx[px] = bk;
    }
}

// ---------------- gather + fused loss (R1-proven) ----------------
__global__ void gather_kernel(const float* __restrict__ z,
                              const float* __restrict__ e,
                              const int* __restrict__ idx,
                              float* __restrict__ out,
                              float* __restrict__ loss) {
    const int t = threadIdx.x;
    const int n0 = blockIdx.x * 64;
    __shared__ int kidx[64];
    if (t < 64) kidx[t] = idx[n0 + t];
    __syncthreads();

    const int p = t & 63;
    const int d0 = t >> 6;
    const size_t base = (size_t)(n0 >> 10) * (DD * HW) + (n0 & (HW - 1)) + p;
    const int kk = kidx[p];

    float acc = 0.f;
    for (int d = d0; d < DD; d += 4) {
        float ev = e[(size_t)d * KN + kk];
        float zv = z[base + (size_t)d * HW];
        out[base + (size_t)d * HW] = zv + (ev - zv);
        float df = ev - zv;
        acc = fmaf(df, df, acc);
    }
#pragma unroll
    for (int off = 32; off > 0; off >>= 1) acc += __shfl_down(acc, off, 64);
    __shared__ float part[4];
    if ((t & 63) == 0) part[t >> 6] = acc;
    __syncthreads();
    if (t == 0) {
        float s = (part[0] + part[1] + part[2] + part[3]) * (1.25f / 8388608.f);
        atomicAdd(loss, s);
    }
}

extern "C" void kernel_launch(void* const* d_in, const int* in_sizes, int n_in,
                              void* d_out, int out_size, void* d_ws, size_t ws_size,
                              hipStream_t stream) {
    const float* z = (const float*)d_in[0];   // [32,256,32,32] fp32
    const float* e = (const float*)d_in[1];   // [256,8192] fp32
    float* out = (float*)d_out;
    float* loss = out + (size_t)NP * DD;      // element 8388608 (byte 32 MiB)

    // Large scratch lives inside d_out (33.55 MB), fully consumed before gather:
    char* ob = (char*)d_out;
    u16*   Acat = (u16*)ob;                          // [0, 16Mi)  bf16 z rows
    u16*   eT   = (u16*)(ob + ((size_t)16 << 20));   // [16Mi, 20Mi) bf16 e^T
    int*   keys = (int*)(ob + ((size_t)20 << 20));   // [20Mi, 20.75Mi) 6 planes
    float* eTf  = (float*)(ob + ((size_t)23 << 20)); // [23Mi, 31Mi) fp32 e^T
    // d_ws: only 160 KB (R1/R4-proven safe)
    float* e2f = (float*)d_ws;                       // 32 KB
    int*   idx = (int*)((char*)d_ws + 32768);        // 128 KB

    enorm_kernel<<<KN / 256, 256, 0, stream>>>(e, e2f);
    prep_eT_kernel<<<dim3(128, 4), 256, 0, stream>>>(e, eT, eTf);
    prep_A_kernel<<<dim3(16, 4, 32), 256, 0, stream>>>(z, Acat);
    argmin_mfma_kernel<<<SPLITS * (NP / PXT), 256, 0, stream>>>(Acat, eT, e2f, keys);
    combine_kernel<<<NP / 64, 256, 0, stream>>>(keys, z, eTf, e2f, idx);
    hipMemsetAsync(loss, 0, sizeof(float), stream);
    gather_kernel<<<NP / 64, 256, 0, stream>>>(z, e, idx, out, loss);
}

// Round 6
// 343.140 us; speedup vs baseline: 1.5944x; 1.5944x over previous
//
#include <hip/hip_runtime.h>

typedef unsigned int u32;
typedef unsigned short u16;
typedef __attribute__((ext_vector_type(8))) short bf16x8;  // 8 bf16 = 4 VGPRs
typedef __attribute__((ext_vector_type(4))) float f32x4;

#define KN 8192
#define DD 256
#define HW 1024
#define NP 32768
#define SPLITS 2
#define KSPLIT 4096
#define PXT 128
#define NTT 128

__device__ __forceinline__ u16 rne_bf16(float x) {
    u32 u = __float_as_uint(x);
    return (u16)((u + 0x7FFF + ((u >> 16) & 1)) >> 16);
}

__device__ __forceinline__ void glds16(const void* g, void* ldsbase) {
    __builtin_amdgcn_global_load_lds((const __attribute__((address_space(1))) u32*)g,
                                     (__attribute__((address_space(3))) u32*)ldsbase, 16, 0, 0);
}

// ---------------- e2f[k] = sum_d e[d,k]^2 (exact fp32) ----------------
__global__ void enorm_kernel(const float* __restrict__ e, float* __restrict__ e2f) {
    int k = blockIdx.x * blockDim.x + threadIdx.x;
    float acc = 0.f;
#pragma unroll 8
    for (int d = 0; d < DD; ++d) {
        float v = e[(size_t)d * KN + k];
        acc = fmaf(v, v, acc);
    }
    e2f[k] = acc;
}

// ------- eT[k][d] = bf16(e[d][k]);  eTf[k][d] = fp32 e[d][k] (for rescoring) -------
__global__ void prep_eT_kernel(const float* __restrict__ e, u16* __restrict__ eT,
                               float* __restrict__ eTf) {
    __shared__ float tt[64][65];
    const int t = threadIdx.x;
    const int kt = blockIdx.x;   // 0..127
    const int dt = blockIdx.y;   // 0..3
    const float* ep = e + (size_t)(dt * 64) * KN + kt * 64;
    {
        int k = t & 63, d0 = t >> 6;
#pragma unroll
        for (int j = 0; j < 16; ++j) tt[d0 + j * 4][k] = ep[(size_t)(d0 + j * 4) * KN + k];
    }
    __syncthreads();
    int k = t >> 2, c0 = (t & 3) * 16;
    u16 hi[16];
    float fv[16];
#pragma unroll
    for (int j = 0; j < 16; ++j) {
        float v = tt[c0 + j][k];
        fv[j] = v;
        hi[j] = rne_bf16(v);
    }
    u16* rowp = eT + (size_t)(kt * 64 + k) * 256 + dt * 64 + c0;
    *(uint4*)(rowp) = *(uint4*)(hi);
    *(uint4*)(rowp + 8) = *(uint4*)(hi + 8);
    float* rowpf = eTf + (size_t)(kt * 64 + k) * 256 + dt * 64 + c0;
#pragma unroll
    for (int j = 0; j < 4; ++j) *(float4*)(rowpf + j * 4) = *(float4*)(fv + j * 4);
}

// ---------------- A[n][d] = bf16(z[b,d,h,w]), n = b*1024 + h*32 + w ----------------
__global__ void prep_A_kernel(const float* __restrict__ z, u16* __restrict__ A) {
    __shared__ float tt[64][65];
    const int t = threadIdx.x;
    const int pt = blockIdx.x;   // 0..15
    const int dt = blockIdx.y;   // 0..3
    const int b  = blockIdx.z;   // 0..31
    const float* zp = z + (size_t)b * (DD * HW) + (size_t)(dt * 64) * HW + pt * 64;
    {
        int p = t & 63, d0 = t >> 6;
#pragma unroll
        for (int j = 0; j < 16; ++j) tt[d0 + j * 4][p] = zp[(size_t)(d0 + j * 4) * HW + p];
    }
    __syncthreads();
    int p = t >> 2, c0 = (t & 3) * 16;
    int n = b * HW + pt * 64 + p;
    u16 hi[16];
#pragma unroll
    for (int j = 0; j < 16; ++j) hi[j] = rne_bf16(tt[c0 + j][p]);
    u16* rowp = A + (size_t)n * 256 + dt * 64 + c0;
    *(uint4*)(rowp) = *(uint4*)(hi);
    *(uint4*)(rowp + 8) = *(uint4*)(hi + 8);
}

// ---------------- main: MFMA distance GEMM + streaming top-3 argmin ----------------
// A tile (128 px x 256 d = 64 KB) stays resident in LDS for the whole kernel,
// staged ONCE as 4 sub-arrays (one per 64-d chunk) in the proven 8-row-group
// layout. Only eT streams through L2 -> per-XCD working set = eT (<=4 MB) fits.
__launch_bounds__(256, 2)
__global__ void argmin_mfma_kernel(const u16* __restrict__ A,   // [32768][256]
                                   const u16* __restrict__ eT,  // [8192][256]
                                   const float* __restrict__ e2f,
                                   int* __restrict__ keys) {    // [3][2][NP]
    __shared__ u16 Ast[4][PXT * 64];  // 64 KB resident A, XOR-swizzled slots
    __shared__ u16 Bst[NTT * 64];     // 16 KB streamed B

    const int t = threadIdx.x;
    const int w = t >> 6;
    const int l = t & 63;
    const int split = blockIdx.x & 1;
    const int pxt   = blockIdx.x >> 1;
    const int px0 = pxt * PXT;
    const int kb0 = split * KSPLIT;

    const int swz  = (l & 7) ^ ((l >> 3) & 7);  // staging: fetch global slot swz
    const int srow = l >> 3;                    // row within 8-row group
    const int fr = l & 15;                      // frag row (m or n)
    const int g  = l >> 4;                      // quad -> k slice g*8..g*8+7

    // stage resident A tile once: 4 d-chunks x 4 row-groups per wave
#pragma unroll
    for (int c = 0; c < 4; ++c)
#pragma unroll
        for (int i = 0; i < 4; ++i) {
            int r0 = w * 32 + i * 8;
            const u16* gp = A + (size_t)(px0 + r0 + srow) * 256 + c * 64 + swz * 8;
            glds16(gp, &Ast[c][r0 * 64]);
        }

    int b1[8], b2[8], b3[8];
#pragma unroll
    for (int i = 0; i < 8; ++i) { b1[i] = 0x7FFFFFFF; b2[i] = 0x7FFFFFFF; b3[i] = 0x7FFFFFFF; }

    for (int nt = 0; nt < KSPLIT / NTT; ++nt) {
        const int n0 = kb0 + nt * NTT;
        f32x4 acc[2][8];
#pragma unroll
        for (int mi = 0; mi < 2; ++mi)
#pragma unroll
            for (int ni = 0; ni < 8; ++ni) acc[mi][ni] = (f32x4){0.f, 0.f, 0.f, 0.f};

        for (int kit = 0; kit < 4; ++kit) {
            __syncthreads();   // Bst safe to overwrite; also drains A stage (vmcnt0)
#pragma unroll
            for (int i = 0; i < 4; ++i) {   // B: 128 codewords x 64 bf16
                int r0 = w * 32 + i * 8;
                const u16* gp = eT + (size_t)(n0 + r0 + srow) * 256 + kit * 64 + swz * 8;
                glds16(gp, &Bst[r0 * 64]);
            }
            __syncthreads();
#pragma unroll
            for (int kc = 0; kc < 2; ++kc) {
                bf16x8 af[2], bfr[8];
#pragma unroll
                for (int mi = 0; mi < 2; ++mi) {
                    int row = w * 32 + mi * 16 + fr;
                    int slt = (kc * 4 + g) ^ (row & 7);
                    af[mi] = *(const bf16x8*)&Ast[kit][row * 64 + slt * 8];
                }
#pragma unroll
                for (int ni = 0; ni < 8; ++ni) {
                    int row = ni * 16 + fr;
                    int slt = (kc * 4 + g) ^ (row & 7);
                    bfr[ni] = *(const bf16x8*)&Bst[row * 64 + slt * 8];
                }
#pragma unroll
                for (int mi = 0; mi < 2; ++mi)
#pragma unroll
                    for (int ni = 0; ni < 8; ++ni)
                        acc[mi][ni] = __builtin_amdgcn_mfma_f32_16x16x32_bf16(
                            af[mi], bfr[ni], acc[mi][ni], 0, 0, 0);
            }
        }

        // epilogue: key = trunc(256*(e2-2s))*8192 + k ; streaming top-3
#pragma unroll
        for (int ni = 0; ni < 8; ++ni) {
            int kcol = n0 + ni * 16 + fr;
            float e2c = e2f[kcol] * 256.f;
#pragma unroll
            for (int mi = 0; mi < 2; ++mi) {
#pragma unroll
                for (int r = 0; r < 4; ++r) {
                    float d = fmaf(acc[mi][ni][r], -512.f, e2c);
                    int key = (int)d * 8192 + kcol;
                    int i8 = mi * 4 + r;
                    int v1 = min(b1[i8], key);
                    int x  = max(b1[i8], key);
                    int v2 = min(b2[i8], x);
                    int y  = max(b2[i8], x);
                    int v3 = min(b3[i8], y);
                    b1[i8] = v1; b2[i8] = v2; b3[i8] = v3;
                }
            }
        }
    }

    // merge top-3 across the 16 fr-lanes (columns); g-groups hold distinct rows
#pragma unroll
    for (int m = 1; m < 16; m <<= 1) {
#pragma unroll
        for (int i = 0; i < 8; ++i) {
            int a1 = __shfl_xor(b1[i], m, 64);
            int a2 = __shfl_xor(b2[i], m, 64);
            int a3 = __shfl_xor(b3[i], m, 64);
            int m1 = min(b1[i], a1);
            int xx = max(b1[i], a1);
            int mn2 = min(b2[i], a2);
            int m2 = min(xx, mn2);
            int m3 = min(min(max(b2[i], a2), max(xx, mn2)), min(b3[i], a3));
            b1[i] = m1; b2[i] = m2; b3[i] = m3;
        }
    }
    if (fr == 0) {
        int* k1 = keys + split * NP;
        int* k2 = keys + (2 + split) * NP;
        int* k3 = keys + (4 + split) * NP;
#pragma unroll
        for (int mi = 0; mi < 2; ++mi)
#pragma unroll
            for (int r = 0; r < 4; ++r) {
                int row = px0 + w * 32 + mi * 16 + g * 4 + r;
                k1[row] = b1[mi * 4 + r];
                k2[row] = b2[mi * 4 + r];
                k3[row] = b3[mi * 4 + r];
            }
    }
}

// -------- combine: ALWAYS exact-rescore all 6 candidates in fp32 --------
__global__ void combine_kernel(const int* __restrict__ keys,
                               const float* __restrict__ z,
                               const float* __restrict__ eTf,
                               const float* __restrict__ e2f,
                               int* __restrict__ idx) {
    __shared__ float zt[DD * 65];     // padded: zt[d*65+p]
    const int t = threadIdx.x;
    const int n0 = blockIdx.x * 64;   // 64 pixels per block
    const float* zp = z + (size_t)(n0 >> 10) * (DD * HW) + (n0 & (HW - 1));
    for (int i = t; i < DD * 64; i += 256) {
        int d = i >> 6, p = i & 63;
        zt[d * 65 + p] = zp[(size_t)d * HW + p];   // coalesced
    }
    __syncthreads();

    const int l = t & 63, w = t >> 6;
    for (int q = 0; q < 16; ++q) {
        const int p = w * 16 + q;
        const int px = n0 + p;
        float zr0 = zt[(l      ) * 65 + p];
        float zr1 = zt[(l +  64) * 65 + p];
        float zr2 = zt[(l + 128) * 65 + p];
        float zr3 = zt[(l + 192) * 65 + p];
        float bv = 3.4e38f;
        int   bk = 0x7FFFFFFF;
#pragma unroll
        for (int c = 0; c < 6; ++c) {
            int k = keys[c * NP + px] & 8191;      // px wave-uniform -> scalar load
            const float* er = eTf + (size_t)k * 256;
            float acc = zr0 * er[l];
            acc = fmaf(zr1, er[l + 64], acc);
            acc = fmaf(zr2, er[l + 128], acc);
            acc = fmaf(zr3, er[l + 192], acc);
#pragma unroll
            for (int m = 1; m < 64; m <<= 1) acc += __shfl_xor(acc, m, 64);
            float d = fmaf(-2.f, acc, e2f[k]);     // exact fp32 (minus const ||z||^2)
            if (d < bv || (d == bv && k < bk)) { bv = d; bk = k; }
        }
        if (l == 0) idx[px] = bk;
    }
}

// ---------------- gather + fused loss (R1-proven) ----------------
__global__ void gather_kernel(const float* __restrict__ z,
                              const float* __restrict__ e,
                              const int* __restrict__ idx,
                              float* __restrict__ out,
                              float* __restrict__ loss) {
    const int t = threadIdx.x;
    const int n0 = blockIdx.x * 64;
    __shared__ int kidx[64];
    if (t < 64) kidx[t] = idx[n0 + t];
    __syncthreads();

    const int p = t & 63;
    const int d0 = t >> 6;
    const size_t base = (size_t)(n0 >> 10) * (DD * HW) + (n0 & (HW - 1)) + p;
    const int kk = kidx[p];

    float acc = 0.f;
    for (int d = d0; d < DD; d += 4) {
        float ev = e[(size_t)d * KN + kk];
        float zv = z[base + (size_t)d * HW];
        out[base + (size_t)d * HW] = zv + (ev - zv);
        float df = ev - zv;
        acc = fmaf(df, df, acc);
    }
#pragma unroll
    for (int off = 32; off > 0; off >>= 1) acc += __shfl_down(acc, off, 64);
    __shared__ float part[4];
    if ((t & 63) == 0) part[t >> 6] = acc;
    __syncthreads();
    if (t == 0) {
        float s = (part[0] + part[1] + part[2] + part[3]) * (1.25f / 8388608.f);
        atomicAdd(loss, s);
    }
}

extern "C" void kernel_launch(void* const* d_in, const int* in_sizes, int n_in,
                              void* d_out, int out_size, void* d_ws, size_t ws_size,
                              hipStream_t stream) {
    const float* z = (const float*)d_in[0];   // [32,256,32,32] fp32
    const float* e = (const float*)d_in[1];   // [256,8192] fp32
    float* out = (float*)d_out;
    float* loss = out + (size_t)NP * DD;      // element 8388608 (byte 32 MiB)

    // Large scratch lives inside d_out (33.55 MB), fully consumed before gather:
    char* ob = (char*)d_out;
    u16*   Acat = (u16*)ob;                          // [0, 16Mi)  bf16 z rows
    u16*   eT   = (u16*)(ob + ((size_t)16 << 20));   // [16Mi, 20Mi) bf16 e^T
    int*   keys = (int*)(ob + ((size_t)20 << 20));   // [20Mi, 20.75Mi) 6 planes
    float* eTf  = (float*)(ob + ((size_t)23 << 20)); // [23Mi, 31Mi) fp32 e^T
    // d_ws: only 160 KB (R1/R4-proven safe)
    float* e2f = (float*)d_ws;                       // 32 KB
    int*   idx = (int*)((char*)d_ws + 32768);        // 128 KB

    enorm_kernel<<<KN / 256, 256, 0, stream>>>(e, e2f);
    prep_eT_kernel<<<dim3(128, 4), 256, 0, stream>>>(e, eT, eTf);
    prep_A_kernel<<<dim3(16, 4, 32), 256, 0, stream>>>(z, Acat);
    argmin_mfma_kernel<<<SPLITS * (NP / PXT), 256, 0, stream>>>(Acat, eT, e2f, keys);
    combine_kernel<<<NP / 64, 256, 0, stream>>>(keys, z, eTf, e2f, idx);
    hipMemsetAsync(loss, 0, sizeof(float), stream);
    gather_kernel<<<NP / 64, 256, 0, stream>>>(z, e, idx, out, loss);
}

// Round 7
// 281.682 us; speedup vs baseline: 1.9423x; 1.2182x over previous
//
#include <hip/hip_runtime.h>

typedef unsigned int u32;
typedef unsigned short u16;
typedef __attribute__((ext_vector_type(8))) short bf16x8;  // 8 bf16 = 4 VGPRs
typedef __attribute__((ext_vector_type(4))) float f32x4;

#define KN 8192
#define DD 256
#define HW 1024
#define NP 32768
#define SPLITS 2
#define KSPLIT 4096
#define PXT 128
#define NTT 128

__device__ __forceinline__ u16 rne_bf16(float x) {
    u32 u = __float_as_uint(x);
    return (u16)((u + 0x7FFF + ((u >> 16) & 1)) >> 16);
}

__device__ __forceinline__ void glds16(const void* g, void* ldsbase) {
    __builtin_amdgcn_global_load_lds((const __attribute__((address_space(1))) u32*)g,
                                     (__attribute__((address_space(3))) u32*)ldsbase, 16, 0, 0);
}

// ---------------- e2f[k] = sum_d e[d,k]^2 (exact fp32) ----------------
__global__ void enorm_kernel(const float* __restrict__ e, float* __restrict__ e2f) {
    int k = blockIdx.x * blockDim.x + threadIdx.x;
    float acc = 0.f;
#pragma unroll 8
    for (int d = 0; d < DD; ++d) {
        float v = e[(size_t)d * KN + k];
        acc = fmaf(v, v, acc);
    }
    e2f[k] = acc;
}

// ------- eT[k][d] = bf16(e[d][k]);  eTf[k][d] = fp32 e[d][k] (for rescoring) -------
__global__ void prep_eT_kernel(const float* __restrict__ e, u16* __restrict__ eT,
                               float* __restrict__ eTf) {
    __shared__ float tt[64][65];
    const int t = threadIdx.x;
    const int kt = blockIdx.x;   // 0..127
    const int dt = blockIdx.y;   // 0..3
    const float* ep = e + (size_t)(dt * 64) * KN + kt * 64;
    {
        int k = t & 63, d0 = t >> 6;
#pragma unroll
        for (int j = 0; j < 16; ++j) tt[d0 + j * 4][k] = ep[(size_t)(d0 + j * 4) * KN + k];
    }
    __syncthreads();
    int k = t >> 2, c0 = (t & 3) * 16;
    u16 hi[16];
    float fv[16];
#pragma unroll
    for (int j = 0; j < 16; ++j) {
        float v = tt[c0 + j][k];
        fv[j] = v;
        hi[j] = rne_bf16(v);
    }
    u16* rowp = eT + (size_t)(kt * 64 + k) * 256 + dt * 64 + c0;
    *(uint4*)(rowp) = *(uint4*)(hi);
    *(uint4*)(rowp + 8) = *(uint4*)(hi + 8);
    float* rowpf = eTf + (size_t)(kt * 64 + k) * 256 + dt * 64 + c0;
#pragma unroll
    for (int j = 0; j < 4; ++j) *(float4*)(rowpf + j * 4) = *(float4*)(fv + j * 4);
}

// ---------------- A[n][d] = bf16(z[b,d,h,w]), n = b*1024 + h*32 + w ----------------
__global__ void prep_A_kernel(const float* __restrict__ z, u16* __restrict__ A) {
    __shared__ float tt[64][65];
    const int t = threadIdx.x;
    const int pt = blockIdx.x;   // 0..15
    const int dt = blockIdx.y;   // 0..3
    const int b  = blockIdx.z;   // 0..31
    const float* zp = z + (size_t)b * (DD * HW) + (size_t)(dt * 64) * HW + pt * 64;
    {
        int p = t & 63, d0 = t >> 6;
#pragma unroll
        for (int j = 0; j < 16; ++j) tt[d0 + j * 4][p] = zp[(size_t)(d0 + j * 4) * HW + p];
    }
    __syncthreads();
    int p = t >> 2, c0 = (t & 3) * 16;
    int n = b * HW + pt * 64 + p;
    u16 hi[16];
#pragma unroll
    for (int j = 0; j < 16; ++j) hi[j] = rne_bf16(tt[c0 + j][p]);
    u16* rowp = A + (size_t)n * 256 + dt * 64 + c0;
    *(uint4*)(rowp) = *(uint4*)(hi);
    *(uint4*)(rowp + 8) = *(uint4*)(hi + 8);
}

// ---------------- main: MFMA distance GEMM + streaming argmin ----------------
// A tile resident in LDS (R6-proven). Epilogue: per-pixel min of the 8 packed
// keys first (min3 tree), then top-2 streaming insert; top-3 extracted at the
// final lane merge (pairs treated as triples with c3=MAX).
__launch_bounds__(256, 2)
__global__ void argmin_mfma_kernel(const u16* __restrict__ A,   // [32768][256]
                                   const u16* __restrict__ eT,  // [8192][256]
                                   const float* __restrict__ e2f,
                                   int* __restrict__ keys) {    // [3][2][NP]
    __shared__ u16 Ast[4][PXT * 64];  // 64 KB resident A, XOR-swizzled slots
    __shared__ u16 Bst[NTT * 64];     // 16 KB streamed B

    const int t = threadIdx.x;
    const int w = t >> 6;
    const int l = t & 63;
    const int split = blockIdx.x & 1;
    const int pxt   = blockIdx.x >> 1;
    const int px0 = pxt * PXT;
    const int kb0 = split * KSPLIT;

    const int swz  = (l & 7) ^ ((l >> 3) & 7);  // staging: fetch global slot swz
    const int srow = l >> 3;                    // row within 8-row group
    const int fr = l & 15;                      // frag row (m or n)
    const int g  = l >> 4;                      // quad -> k slice g*8..g*8+7

    // stage resident A tile once: 4 d-chunks x 4 row-groups per wave
#pragma unroll
    for (int c = 0; c < 4; ++c)
#pragma unroll
        for (int i = 0; i < 4; ++i) {
            int r0 = w * 32 + i * 8;
            const u16* gp = A + (size_t)(px0 + r0 + srow) * 256 + c * 64 + swz * 8;
            glds16(gp, &Ast[c][r0 * 64]);
        }

    int b1[8], b2[8];
#pragma unroll
    for (int i = 0; i < 8; ++i) { b1[i] = 0x7FFFFFFF; b2[i] = 0x7FFFFFFF; }

    for (int nt = 0; nt < KSPLIT / NTT; ++nt) {
        const int n0 = kb0 + nt * NTT;
        f32x4 acc[2][8];
#pragma unroll
        for (int mi = 0; mi < 2; ++mi)
#pragma unroll
            for (int ni = 0; ni < 8; ++ni) acc[mi][ni] = (f32x4){0.f, 0.f, 0.f, 0.f};

        for (int kit = 0; kit < 4; ++kit) {
            __syncthreads();   // Bst safe to overwrite; also drains A stage
#pragma unroll
            for (int i = 0; i < 4; ++i) {   // B: 128 codewords x 64 bf16
                int r0 = w * 32 + i * 8;
                const u16* gp = eT + (size_t)(n0 + r0 + srow) * 256 + kit * 64 + swz * 8;
                glds16(gp, &Bst[r0 * 64]);
            }
            __syncthreads();
#pragma unroll
            for (int kc = 0; kc < 2; ++kc) {
                bf16x8 af[2], bfr[8];
#pragma unroll
                for (int mi = 0; mi < 2; ++mi) {
                    int row = w * 32 + mi * 16 + fr;
                    int slt = (kc * 4 + g) ^ (row & 7);
                    af[mi] = *(const bf16x8*)&Ast[kit][row * 64 + slt * 8];
                }
#pragma unroll
                for (int ni = 0; ni < 8; ++ni) {
                    int row = ni * 16 + fr;
                    int slt = (kc * 4 + g) ^ (row & 7);
                    bfr[ni] = *(const bf16x8*)&Bst[row * 64 + slt * 8];
                }
#pragma unroll
                for (int mi = 0; mi < 2; ++mi)
#pragma unroll
                    for (int ni = 0; ni < 8; ++ni)
                        acc[mi][ni] = __builtin_amdgcn_mfma_f32_16x16x32_bf16(
                            af[mi], bfr[ni], acc[mi][ni], 0, 0, 0);
            }
        }

        // epilogue: key = trunc(256*(e2-2s))*8192 + k
        float e2c[8];
        int   kc8[8];
#pragma unroll
        for (int ni = 0; ni < 8; ++ni) {
            kc8[ni] = n0 + ni * 16 + fr;
            e2c[ni] = e2f[kc8[ni]] * 256.f;
        }
#pragma unroll
        for (int mi = 0; mi < 2; ++mi)
#pragma unroll
            for (int r = 0; r < 4; ++r) {
                int ky[8];
#pragma unroll
                for (int ni = 0; ni < 8; ++ni) {
                    float d = fmaf(acc[mi][ni][r], -512.f, e2c[ni]);
                    ky[ni] = (int)d * 8192 + kc8[ni];
                }
                int m0 = min(min(ky[0], ky[1]), ky[2]);
                int m1 = min(min(ky[3], ky[4]), ky[5]);
                int m2 = min(min(ky[6], ky[7]), m0);
                int kmin = min(m1, m2);
                int i8 = mi * 4 + r;
                int v1 = min(b1[i8], kmin);
                int x  = max(b1[i8], kmin);
                b2[i8] = min(b2[i8], x);
                b1[i8] = v1;
            }
    }

    // extract top-3 across the 16 fr-lanes from per-lane sorted pairs
    if (true) {
        int* k1 = keys + split * NP;
        int* k2 = keys + (2 + split) * NP;
        int* k3 = keys + (4 + split) * NP;
#pragma unroll
        for (int i = 0; i < 8; ++i) {
            int c1 = b1[i], c2 = b2[i], c3 = 0x7FFFFFFF;
#pragma unroll
            for (int m = 1; m < 16; m <<= 1) {
                int a1 = __shfl_xor(c1, m, 64);
                int a2 = __shfl_xor(c2, m, 64);
                int a3 = __shfl_xor(c3, m, 64);
                int m1 = min(c1, a1);
                int xx = max(c1, a1);
                int mn2 = min(c2, a2);
                int m2 = min(xx, mn2);
                int m3 = min(min(max(c2, a2), max(xx, mn2)), min(c3, a3));
                c1 = m1; c2 = m2; c3 = m3;
            }
            if (fr == 0) {
                int mi = i >> 2, r = i & 3;
                int row = px0 + w * 32 + mi * 16 + g * 4 + r;
                k1[row] = c1;
                k2[row] = c2;
                k3[row] = c3;
            }
        }
    }
}

// -------- combine: exact fp32 rescore of all 6 candidates, 16-lane dots --------
__global__ void combine_kernel(const int* __restrict__ keys,
                               const float* __restrict__ z,
                               const float* __restrict__ eTf,
                               const float* __restrict__ e2f,
                               int* __restrict__ idx) {
    __shared__ float zt[DD * 65];     // [d][p] padded
    __shared__ int   kc[384];
    __shared__ float dval[384];
    const int t = threadIdx.x;
    const int n0 = blockIdx.x * 64;   // 64 pixels per block
    const float* zp = z + (size_t)(n0 >> 10) * (DD * HW) + (n0 & (HW - 1));
    for (int i = t; i < DD * 64; i += 256) {
        int d = i >> 6, p = i & 63;
        zt[d * 65 + p] = zp[(size_t)d * HW + p];   // coalesced
    }
    for (int i = t; i < 384; i += 256)
        kc[i] = keys[(i % 6) * NP + n0 + i / 6] & 8191;
    __syncthreads();

    const int l = t & 63, w = t >> 6;
    const int j = l & 15;   // lane within 16-lane dot group
    const int s = l >> 4;   // dot-group id within wave
#pragma unroll 2
    for (int it = 0; it < 24; ++it) {
        int dot = it * 16 + w * 4 + s;      // 0..383
        int p = dot / 6, c = dot - p * 6;
        (void)c;
        int k = kc[dot];
        const float* er = eTf + (size_t)k * 256;
        float a = 0.f;
#pragma unroll
        for (int cc = 0; cc < 16; ++cc)
            a = fmaf(zt[(cc * 16 + j) * 65 + p], er[cc * 16 + j], a);
        a += __shfl_xor(a, 1, 64);
        a += __shfl_xor(a, 2, 64);
        a += __shfl_xor(a, 4, 64);
        a += __shfl_xor(a, 8, 64);
        if (j == 0) dval[dot] = fmaf(-2.f, a, e2f[k]);
    }
    __syncthreads();
    if (t < 64) {
        float bv = dval[t * 6];
        int   bk = kc[t * 6];
#pragma unroll
        for (int c = 1; c < 6; ++c) {
            float dv = dval[t * 6 + c];
            int   kk = kc[t * 6 + c];
            if (dv < bv || (dv == bv && kk < bk)) { bv = dv; bk = kk; }
        }
        idx[n0 + t] = bk;
    }
}

// ------- gather fast path: contiguous eTf rows via LDS (eTf in d_ws) -------
__global__ void gather_fast_kernel(const float* __restrict__ z,
                                   const float* __restrict__ eTf,
                                   const int* __restrict__ idx,
                                   float* __restrict__ out,
                                   float* __restrict__ loss) {
    __shared__ float qt[64 * 257];   // [px][d], pad 257 (257%32==1: conflict-free)
    __shared__ int kidx[64];
    const int t = threadIdx.x;
    const int n0 = blockIdx.x * 64;
    if (t < 64) kidx[t] = idx[n0 + t];
    __syncthreads();
    for (int m = 0; m < 64; ++m)     // row m: 256 threads read the full 1 KB row
        qt[m * 257 + t] = eTf[(size_t)kidx[m] * 256 + t];
    __syncthreads();

    const int p = t & 63, q = t >> 6;
    const size_t base = (size_t)(n0 >> 10) * (DD * HW) + (n0 & (HW - 1)) + p;
    float acc = 0.f;
#pragma unroll 8
    for (int i = 0; i < 64; ++i) {
        int d = q * 64 + i;
        float ev = qt[p * 257 + d];
        float zv = z[base + (size_t)d * HW];
        out[base + (size_t)d * HW] = zv + (ev - zv);
        float df = ev - zv;
        acc = fmaf(df, df, acc);
    }
#pragma unroll
    for (int off = 32; off > 0; off >>= 1) acc += __shfl_down(acc, off, 64);
    __shared__ float part[4];
    if ((t & 63) == 0) part[t >> 6] = acc;
    __syncthreads();
    if (t == 0) {
        float s = (part[0] + part[1] + part[2] + part[3]) * (1.25f / 8388608.f);
        atomicAdd(loss, s);
    }
}

// ------- gather slow path (R6-proven): e column gathers, eTf may be in d_out -------
__global__ void gather_slow_kernel(const float* __restrict__ z,
                                   const float* __restrict__ e,
                                   const int* __restrict__ idx,
                                   float* __restrict__ out,
                                   float* __restrict__ loss) {
    const int t = threadIdx.x;
    const int n0 = blockIdx.x * 64;
    __shared__ int kidx[64];
    if (t < 64) kidx[t] = idx[n0 + t];
    __syncthreads();

    const int p = t & 63;
    const int d0 = t >> 6;
    const size_t base = (size_t)(n0 >> 10) * (DD * HW) + (n0 & (HW - 1)) + p;
    const int kk = kidx[p];

    float acc = 0.f;
    for (int d = d0; d < DD; d += 4) {
        float ev = e[(size_t)d * KN + kk];
        float zv = z[base + (size_t)d * HW];
        out[base + (size_t)d * HW] = zv + (ev - zv);
        float df = ev - zv;
        acc = fmaf(df, df, acc);
    }
#pragma unroll
    for (int off = 32; off > 0; off >>= 1) acc += __shfl_down(acc, off, 64);
    __shared__ float part[4];
    if ((t & 63) == 0) part[t >> 6] = acc;
    __syncthreads();
    if (t == 0) {
        float s = (part[0] + part[1] + part[2] + part[3]) * (1.25f / 8388608.f);
        atomicAdd(loss, s);
    }
}

extern "C" void kernel_launch(void* const* d_in, const int* in_sizes, int n_in,
                              void* d_out, int out_size, void* d_ws, size_t ws_size,
                              hipStream_t stream) {
    const float* z = (const float*)d_in[0];   // [32,256,32,32] fp32
    const float* e = (const float*)d_in[1];   // [256,8192] fp32
    float* out = (float*)d_out;
    float* loss = out + (size_t)NP * DD;      // element 8388608

    char* ob = (char*)d_out;
    char* ws = (char*)d_ws;
    // Acat/eT always in d_out (read only by argmin, before any out-writes):
    u16* Acat = (u16*)ob;                            // [0, 16Mi)
    u16* eT   = (u16*)(ob + ((size_t)16 << 20));     // [16Mi, 20Mi)

    float* e2f = (float*)ws;                         // 32 KB (proven-safe region)
    int*   idx = (int*)(ws + (32 << 10));            // 128 KB
    int*   keys;
    float* eTf;
    const bool fastws = ws_size >= ((size_t)10 << 20);
    if (fastws) {
        keys = (int*)(ws + (160 << 10));             // 768 KB @ 160K
        eTf  = (float*)(ws + ((size_t)1 << 20));     // 8 MB @ 1M
    } else {
        keys = (int*)(ob + ((size_t)20 << 20));      // d_out scratch (R6-proven)
        eTf  = (float*)(ob + ((size_t)23 << 20));
    }

    enorm_kernel<<<KN / 256, 256, 0, stream>>>(e, e2f);
    prep_eT_kernel<<<dim3(128, 4), 256, 0, stream>>>(e, eT, eTf);
    prep_A_kernel<<<dim3(16, 4, 32), 256, 0, stream>>>(z, Acat);
    argmin_mfma_kernel<<<SPLITS * (NP / PXT), 256, 0, stream>>>(Acat, eT, e2f, keys);
    combine_kernel<<<NP / 64, 256, 0, stream>>>(keys, z, eTf, e2f, idx);
    hipMemsetAsync(loss, 0, sizeof(float), stream);
    if (fastws)
        gather_fast_kernel<<<NP / 64, 256, 0, stream>>>(z, eTf, idx, out, loss);
    else
        gather_slow_kernel<<<NP / 64, 256, 0, stream>>>(z, e, idx, out, loss);
}

// Round 8
// 267.806 us; speedup vs baseline: 2.0429x; 1.0518x over previous
//
#include <hip/hip_runtime.h>

typedef unsigned int u32;
typedef unsigned short u16;
typedef __attribute__((ext_vector_type(8))) short bf16x8;  // 8 bf16 = 4 VGPRs
typedef __attribute__((ext_vector_type(4))) float f32x4;

#define KN 8192
#define DD 256
#define HW 1024
#define NP 32768
#define SPLITS 2
#define KSPLIT 4096
#define PXT 128
#define NTT 128

__device__ __forceinline__ u16 rne_bf16(float x) {
    u32 u = __float_as_uint(x);
    return (u16)((u + 0x7FFF + ((u >> 16) & 1)) >> 16);
}

__device__ __forceinline__ void glds16(const void* g, void* ldsbase) {
    __builtin_amdgcn_global_load_lds((const __attribute__((address_space(1))) u32*)g,
                                     (__attribute__((address_space(3))) u32*)ldsbase, 16, 0, 0);
}

// ---------------- merged prep: enorm | eT/eTf transpose | A build ----------------
// bid <32: e2f.  bid in [32,544): prep_eT (kt,dt).  bid in [544,2592): prep_A.
__global__ void prep_kernel(const float* __restrict__ e, const float* __restrict__ z,
                            u16* __restrict__ eT, float* __restrict__ eTf,
                            float* __restrict__ e2f, u16* __restrict__ A) {
    const int t = threadIdx.x;
    const int bid = blockIdx.x;
    if (bid < 32) {
        int k = bid * 256 + t;
        float acc = 0.f;
#pragma unroll 8
        for (int d = 0; d < DD; ++d) {
            float v = e[(size_t)d * KN + k];
            acc = fmaf(v, v, acc);
        }
        e2f[k] = acc;
    } else if (bid < 544) {
        __shared__ float tt[64][65];
        const int b2 = bid - 32;
        const int kt = b2 & 127;     // 0..127
        const int dt = b2 >> 7;      // 0..3
        const float* ep = e + (size_t)(dt * 64) * KN + kt * 64;
        {
            int k = t & 63, d0 = t >> 6;
#pragma unroll
            for (int j = 0; j < 16; ++j) tt[d0 + j * 4][k] = ep[(size_t)(d0 + j * 4) * KN + k];
        }
        __syncthreads();
        int k = t >> 2, c0 = (t & 3) * 16;
        u16 hi[16];
        float fv[16];
#pragma unroll
        for (int j = 0; j < 16; ++j) {
            float v = tt[c0 + j][k];
            fv[j] = v;
            hi[j] = rne_bf16(v);
        }
        u16* rowp = eT + (size_t)(kt * 64 + k) * 256 + dt * 64 + c0;
        *(uint4*)(rowp) = *(uint4*)(hi);
        *(uint4*)(rowp + 8) = *(uint4*)(hi + 8);
        float* rowpf = eTf + (size_t)(kt * 64 + k) * 256 + dt * 64 + c0;
#pragma unroll
        for (int j = 0; j < 4; ++j) *(float4*)(rowpf + j * 4) = *(float4*)(fv + j * 4);
    } else {
        __shared__ float tt[64][65];
        const int b3 = bid - 544;
        const int pt = b3 & 15;          // 0..15
        const int dt = (b3 >> 4) & 3;    // 0..3
        const int b  = b3 >> 6;          // 0..31
        const float* zp = z + (size_t)b * (DD * HW) + (size_t)(dt * 64) * HW + pt * 64;
        {
            int p = t & 63, d0 = t >> 6;
#pragma unroll
            for (int j = 0; j < 16; ++j) tt[d0 + j * 4][p] = zp[(size_t)(d0 + j * 4) * HW + p];
        }
        __syncthreads();
        int p = t >> 2, c0 = (t & 3) * 16;
        int n = b * HW + pt * 64 + p;
        u16 hi[16];
#pragma unroll
        for (int j = 0; j < 16; ++j) hi[j] = rne_bf16(tt[c0 + j][p]);
        u16* rowp = A + (size_t)n * 256 + dt * 64 + c0;
        *(uint4*)(rowp) = *(uint4*)(hi);
        *(uint4*)(rowp + 8) = *(uint4*)(hi + 8);
    }
}

// ---------------- main: MFMA distance GEMM + streaming argmin (R7-proven) ----------------
__launch_bounds__(256, 2)
__global__ void argmin_mfma_kernel(const u16* __restrict__ A,   // [32768][256]
                                   const u16* __restrict__ eT,  // [8192][256]
                                   const float* __restrict__ e2f,
                                   int* __restrict__ keys) {    // [3][2][NP]
    __shared__ u16 Ast[4][PXT * 64];  // 64 KB resident A, XOR-swizzled slots
    __shared__ u16 Bst[NTT * 64];     // 16 KB streamed B

    const int t = threadIdx.x;
    const int w = t >> 6;
    const int l = t & 63;
    const int split = blockIdx.x & 1;
    const int pxt   = blockIdx.x >> 1;
    const int px0 = pxt * PXT;
    const int kb0 = split * KSPLIT;

    const int swz  = (l & 7) ^ ((l >> 3) & 7);
    const int srow = l >> 3;
    const int fr = l & 15;
    const int g  = l >> 4;

#pragma unroll
    for (int c = 0; c < 4; ++c)
#pragma unroll
        for (int i = 0; i < 4; ++i) {
            int r0 = w * 32 + i * 8;
            const u16* gp = A + (size_t)(px0 + r0 + srow) * 256 + c * 64 + swz * 8;
            glds16(gp, &Ast[c][r0 * 64]);
        }

    int b1[8], b2[8];
#pragma unroll
    for (int i = 0; i < 8; ++i) { b1[i] = 0x7FFFFFFF; b2[i] = 0x7FFFFFFF; }

    for (int nt = 0; nt < KSPLIT / NTT; ++nt) {
        const int n0 = kb0 + nt * NTT;
        f32x4 acc[2][8];
#pragma unroll
        for (int mi = 0; mi < 2; ++mi)
#pragma unroll
            for (int ni = 0; ni < 8; ++ni) acc[mi][ni] = (f32x4){0.f, 0.f, 0.f, 0.f};

        for (int kit = 0; kit < 4; ++kit) {
            __syncthreads();
#pragma unroll
            for (int i = 0; i < 4; ++i) {
                int r0 = w * 32 + i * 8;
                const u16* gp = eT + (size_t)(n0 + r0 + srow) * 256 + kit * 64 + swz * 8;
                glds16(gp, &Bst[r0 * 64]);
            }
            __syncthreads();
#pragma unroll
            for (int kc = 0; kc < 2; ++kc) {
                bf16x8 af[2], bfr[8];
#pragma unroll
                for (int mi = 0; mi < 2; ++mi) {
                    int row = w * 32 + mi * 16 + fr;
                    int slt = (kc * 4 + g) ^ (row & 7);
                    af[mi] = *(const bf16x8*)&Ast[kit][row * 64 + slt * 8];
                }
#pragma unroll
                for (int ni = 0; ni < 8; ++ni) {
                    int row = ni * 16 + fr;
                    int slt = (kc * 4 + g) ^ (row & 7);
                    bfr[ni] = *(const bf16x8*)&Bst[row * 64 + slt * 8];
                }
#pragma unroll
                for (int mi = 0; mi < 2; ++mi)
#pragma unroll
                    for (int ni = 0; ni < 8; ++ni)
                        acc[mi][ni] = __builtin_amdgcn_mfma_f32_16x16x32_bf16(
                            af[mi], bfr[ni], acc[mi][ni], 0, 0, 0);
            }
        }

        float e2c[8];
        int   kc8[8];
#pragma unroll
        for (int ni = 0; ni < 8; ++ni) {
            kc8[ni] = n0 + ni * 16 + fr;
            e2c[ni] = e2f[kc8[ni]] * 256.f;
        }
#pragma unroll
        for (int mi = 0; mi < 2; ++mi)
#pragma unroll
            for (int r = 0; r < 4; ++r) {
                int ky[8];
#pragma unroll
                for (int ni = 0; ni < 8; ++ni) {
                    float d = fmaf(acc[mi][ni][r], -512.f, e2c[ni]);
                    ky[ni] = (int)d * 8192 + kc8[ni];
                }
                int m0 = min(min(ky[0], ky[1]), ky[2]);
                int m1 = min(min(ky[3], ky[4]), ky[5]);
                int m2 = min(min(ky[6], ky[7]), m0);
                int kmin = min(m1, m2);
                int i8 = mi * 4 + r;
                int v1 = min(b1[i8], kmin);
                int x  = max(b1[i8], kmin);
                b2[i8] = min(b2[i8], x);
                b1[i8] = v1;
            }
    }

    {
        int* k1 = keys + split * NP;
        int* k2 = keys + (2 + split) * NP;
        int* k3 = keys + (4 + split) * NP;
#pragma unroll
        for (int i = 0; i < 8; ++i) {
            int c1 = b1[i], c2 = b2[i], c3 = 0x7FFFFFFF;
#pragma unroll
            for (int m = 1; m < 16; m <<= 1) {
                int a1 = __shfl_xor(c1, m, 64);
                int a2 = __shfl_xor(c2, m, 64);
                int a3 = __shfl_xor(c3, m, 64);
                int m1 = min(c1, a1);
                int xx = max(c1, a1);
                int mn2 = min(c2, a2);
                int m2 = min(xx, mn2);
                int m3 = min(min(max(c2, a2), max(xx, mn2)), min(c3, a3));
                c1 = m1; c2 = m2; c3 = m3;
            }
            if (fr == 0) {
                int mi = i >> 2, r = i & 3;
                int row = px0 + w * 32 + mi * 16 + g * 4 + r;
                k1[row] = c1;
                k2[row] = c2;
                k3[row] = c3;
            }
        }
    }
}

// -------- finalize (fast-ws): dots + select + gather + out + loss, one pass --------
__global__ void finalize_kernel(const int* __restrict__ keys,
                                const float* __restrict__ z,
                                const float* __restrict__ eTf,
                                const float* __restrict__ e2f,
                                float* __restrict__ out,
                                float* __restrict__ loss) {
    __shared__ float smem[DD * 65];   // phase 1: zt[d*65+p]; phase 2: qt[p*257+d]
    __shared__ int   kc[384];
    __shared__ float dval[384];
    __shared__ int   kidx[64];
    const int t = threadIdx.x;
    const int n0 = blockIdx.x * 64;
    const float* zp = z + (size_t)(n0 >> 10) * (DD * HW) + (n0 & (HW - 1));

    for (int i = t; i < DD * 64; i += 256) {
        int d = i >> 6, p = i & 63;
        smem[d * 65 + p] = zp[(size_t)d * HW + p];   // coalesced
    }
    for (int i = t; i < 384; i += 256)
        kc[i] = keys[(i % 6) * NP + n0 + i / 6] & 8191;
    __syncthreads();

    const int l = t & 63, w = t >> 6;
    const int j = l & 15;   // lane within 16-lane dot group
    const int s = l >> 4;   // dot-group id within wave
#pragma unroll 2
    for (int it = 0; it < 24; ++it) {
        int dot = it * 16 + w * 4 + s;      // 0..383
        int p = dot / 6;
        int k = kc[dot];
        const float* er = eTf + (size_t)k * 256;
        float a = 0.f;
#pragma unroll
        for (int cc = 0; cc < 16; ++cc)
            a = fmaf(smem[(cc * 16 + j) * 65 + p], er[cc * 16 + j], a);
        a += __shfl_xor(a, 1, 64);
        a += __shfl_xor(a, 2, 64);
        a += __shfl_xor(a, 4, 64);
        a += __shfl_xor(a, 8, 64);
        if (j == 0) dval[dot] = fmaf(-2.f, a, e2f[k]);
    }
    __syncthreads();
    if (t < 64) {
        float bv = dval[t * 6];
        int   bk = kc[t * 6];
#pragma unroll
        for (int c = 1; c < 6; ++c) {
            float dv = dval[t * 6 + c];
            int   kk = kc[t * 6 + c];
            if (dv < bv || (dv == bv && kk < bk)) { bv = dv; bk = kk; }
        }
        kidx[t] = bk;
    }
    __syncthreads();

    // phase 2: bounce the 64 winning eTf rows through smem (zt is dead)
    float* qt = smem;                 // [p][d] pad 257 (257%32==1: conflict-free)
    for (int m = 0; m < 64; ++m)      // row m: 256 threads read the 1 KB row
        qt[m * 257 + t] = eTf[(size_t)kidx[m] * 256 + t];
    __syncthreads();

    const int p = t & 63, q = t >> 6;
    const size_t base = (size_t)(n0 >> 10) * (DD * HW) + (n0 & (HW - 1)) + p;
    float acc = 0.f;
#pragma unroll 8
    for (int i = 0; i < 64; ++i) {
        int d = q * 64 + i;
        float ev = qt[p * 257 + d];
        float zv = z[base + (size_t)d * HW];   // coalesced, L2-hot re-read
        out[base + (size_t)d * HW] = zv + (ev - zv);
        float df = ev - zv;
        acc = fmaf(df, df, acc);
    }
#pragma unroll
    for (int off = 32; off > 0; off >>= 1) acc += __shfl_down(acc, off, 64);
    __shared__ float part[4];
    if ((t & 63) == 0) part[t >> 6] = acc;
    __syncthreads();
    if (t == 0) {
        float s2 = (part[0] + part[1] + part[2] + part[3]) * (1.25f / 8388608.f);
        atomicAdd(loss, s2);
    }
}

// -------- slow-ws path: R7-proven separate combine + gather --------
__global__ void combine_kernel(const int* __restrict__ keys,
                               const float* __restrict__ z,
                               const float* __restrict__ eTf,
                               const float* __restrict__ e2f,
                               int* __restrict__ idx) {
    __shared__ float zt[DD * 65];
    __shared__ int   kc[384];
    __shared__ float dval[384];
    const int t = threadIdx.x;
    const int n0 = blockIdx.x * 64;
    const float* zp = z + (size_t)(n0 >> 10) * (DD * HW) + (n0 & (HW - 1));
    for (int i = t; i < DD * 64; i += 256) {
        int d = i >> 6, p = i & 63;
        zt[d * 65 + p] = zp[(size_t)d * HW + p];
    }
    for (int i = t; i < 384; i += 256)
        kc[i] = keys[(i % 6) * NP + n0 + i / 6] & 8191;
    __syncthreads();

    const int l = t & 63, w = t >> 6;
    const int j = l & 15;
    const int s = l >> 4;
#pragma unroll 2
    for (int it = 0; it < 24; ++it) {
        int dot = it * 16 + w * 4 + s;
        int p = dot / 6;
        int k = kc[dot];
        const float* er = eTf + (size_t)k * 256;
        float a = 0.f;
#pragma unroll
        for (int cc = 0; cc < 16; ++cc)
            a = fmaf(zt[(cc * 16 + j) * 65 + p], er[cc * 16 + j], a);
        a += __shfl_xor(a, 1, 64);
        a += __shfl_xor(a, 2, 64);
        a += __shfl_xor(a, 4, 64);
        a += __shfl_xor(a, 8, 64);
        if (j == 0) dval[dot] = fmaf(-2.f, a, e2f[k]);
    }
    __syncthreads();
    if (t < 64) {
        float bv = dval[t * 6];
        int   bk = kc[t * 6];
#pragma unroll
        for (int c = 1; c < 6; ++c) {
            float dv = dval[t * 6 + c];
            int   kk = kc[t * 6 + c];
            if (dv < bv || (dv == bv && kk < bk)) { bv = dv; bk = kk; }
        }
        idx[n0 + t] = bk;
    }
}

__global__ void gather_slow_kernel(const float* __restrict__ z,
                                   const float* __restrict__ e,
                                   const int* __restrict__ idx,
                                   float* __restrict__ out,
                                   float* __restrict__ loss) {
    const int t = threadIdx.x;
    const int n0 = blockIdx.x * 64;
    __shared__ int kidx[64];
    if (t < 64) kidx[t] = idx[n0 + t];
    __syncthreads();

    const int p = t & 63;
    const int d0 = t >> 6;
    const size_t base = (size_t)(n0 >> 10) * (DD * HW) + (n0 & (HW - 1)) + p;
    const int kk = kidx[p];

    float acc = 0.f;
    for (int d = d0; d < DD; d += 4) {
        float ev = e[(size_t)d * KN + kk];
        float zv = z[base + (size_t)d * HW];
        out[base + (size_t)d * HW] = zv + (ev - zv);
        float df = ev - zv;
        acc = fmaf(df, df, acc);
    }
#pragma unroll
    for (int off = 32; off > 0; off >>= 1) acc += __shfl_down(acc, off, 64);
    __shared__ float part[4];
    if ((t & 63) == 0) part[t >> 6] = acc;
    __syncthreads();
    if (t == 0) {
        float s = (part[0] + part[1] + part[2] + part[3]) * (1.25f / 8388608.f);
        atomicAdd(loss, s);
    }
}

extern "C" void kernel_launch(void* const* d_in, const int* in_sizes, int n_in,
                              void* d_out, int out_size, void* d_ws, size_t ws_size,
                              hipStream_t stream) {
    const float* z = (const float*)d_in[0];   // [32,256,32,32] fp32
    const float* e = (const float*)d_in[1];   // [256,8192] fp32
    float* out = (float*)d_out;
    float* loss = out + (size_t)NP * DD;      // element 8388608

    char* ob = (char*)d_out;
    char* ws = (char*)d_ws;
    u16* Acat = (u16*)ob;                            // [0, 16Mi) — consumed by argmin
    u16* eT   = (u16*)(ob + ((size_t)16 << 20));     // [16Mi, 20Mi) — consumed by argmin

    float* e2f = (float*)ws;                         // 32 KB (proven-safe region)
    int*   idx = (int*)(ws + (32 << 10));            // 128 KB
    int*   keys;
    float* eTf;
    const bool fastws = ws_size >= ((size_t)10 << 20);
    if (fastws) {
        keys = (int*)(ws + (160 << 10));             // 768 KB @ 160K
        eTf  = (float*)(ws + ((size_t)1 << 20));     // 8 MB @ 1M
    } else {
        keys = (int*)(ob + ((size_t)20 << 20));      // d_out scratch (R6-proven)
        eTf  = (float*)(ob + ((size_t)23 << 20));
    }

    prep_kernel<<<2592, 256, 0, stream>>>(e, z, eT, eTf, e2f, Acat);
    argmin_mfma_kernel<<<SPLITS * (NP / PXT), 256, 0, stream>>>(Acat, eT, e2f, keys);
    hipMemsetAsync(loss, 0, sizeof(float), stream);
    if (fastws) {
        finalize_kernel<<<NP / 64, 256, 0, stream>>>(keys, z, eTf, e2f, out, loss);
    } else {
        combine_kernel<<<NP / 64, 256, 0, stream>>>(keys, z, eTf, e2f, idx);
        gather_slow_kernel<<<NP / 64, 256, 0, stream>>>(z, e, idx, out, loss);
    }
}